// Round 2
// baseline (2061.342 us; speedup 1.0000x reference)
//
#include <hip/hip_runtime.h>

// ---------------------------------------------------------------------------
// GCNModelWPathways: 3-layer GCN (N nodes, BS=8 batch, H=64) + committee
// pathway pooling + 2-layer MLP head + log_softmax.
//
// Decomposition:
//   1. degree count + CSR build (by dst) + dinv = rsqrt(deg+1)
//   2. per layer: register-tiled linear GEMM, then pull-aggregate
//      (block-per-node, thread=(b,h)), fused ReLU+bias and fused fc_w
//      projection into q[N,BS] (mean/linear commute).
//   3. pathway scatter: s_sum[c,b] += q[row[r],b] (atomics, tiny dst buffer)
//   4. head: per-b MLP 400->200->2 + log_softmax.
// ---------------------------------------------------------------------------

__global__ void count_kernel(const int* __restrict__ dst, int* __restrict__ degi, int E) {
  int e = blockIdx.x * blockDim.x + threadIdx.x;
  if (e < E) atomicAdd(&degi[dst[e]], 1);
}

// single-block exclusive prefix sum over counts[0..n) -> row_start[0..n]
__global__ void prefix_kernel(const int* __restrict__ counts, int* __restrict__ row_start, int n) {
  __shared__ int sums[1024];
  int t = threadIdx.x;
  int chunk = (n + 1023) >> 10;
  int beg = t * chunk;
  int end = min(beg + chunk, n);
  int s = 0;
  for (int i = beg; i < end; ++i) s += counts[i];
  sums[t] = s;
  __syncthreads();
  for (int d = 1; d < 1024; d <<= 1) {
    int v = (t >= d) ? sums[t - d] : 0;
    __syncthreads();
    sums[t] += v;
    __syncthreads();
  }
  int off = (t == 0) ? 0 : sums[t - 1];
  for (int i = beg; i < end; ++i) { row_start[i] = off; off += counts[i]; }
  if (end == n) row_start[n] = off;  // all such threads write the total
}

__global__ void fill_kernel(const int* __restrict__ src, const int* __restrict__ dst,
                            const int* __restrict__ row_start, int* __restrict__ cursor,
                            int* __restrict__ csr, int E) {
  int e = blockIdx.x * blockDim.x + threadIdx.x;
  if (e < E) {
    int d = dst[e];
    int pos = atomicAdd(&cursor[d], 1);
    csr[row_start[d] + pos] = src[e];
  }
}

__global__ void dinv_kernel(const int* __restrict__ degi, float* __restrict__ dinv, int N) {
  int n = blockIdx.x * blockDim.x + threadIdx.x;
  if (n < N) dinv[n] = rsqrtf((float)(degi[n] + 1));  // +1: self-loop
}

// Register-tiled linear: m[r][h] = sum_f X[r][f] * W[h][f], rows = N*BS.
// Block: 64 rows x 64 h, 256 threads, each computes a 4x4 tile.
// LDS rows padded to 68 floats -> every ds_read_b128 is <=2-way (free).
// FROM_X: input is x with layout [BS, N, F] (transpose folded into gather).
template <bool FROM_X>
__global__ void linear_kernel(const float* __restrict__ hin, const float* __restrict__ W,
                              float* __restrict__ m, int N, int BS) {
  __shared__ __align__(16) float Xs[64][68];
  __shared__ __align__(16) float Wt[64][68];  // Wt[f][h]
  int t = threadIdx.x;
  int rows_total = N * BS;
  int row0 = blockIdx.x * 64;
  int nrows = min(64, rows_total - row0);

  // stage W transposed (coalesced read, scattered LDS write; once per block)
  for (int i = t; i < 4096; i += 256) {
    int h = i >> 6, f = i & 63;
    Wt[f][h] = W[i];
  }
  // stage X tile: 4 threads per row, each covers 4 float4s (stride 4)
  {
    int rr = t >> 2;   // 0..63
    int c0 = t & 3;
    if (rr < nrows) {
      int g = row0 + rr;
      const float* src;
      if (FROM_X) { int n = g / BS, b = g - n * BS; src = hin + ((size_t)b * N + n) * 64; }
      else        { src = hin + (size_t)g * 64; }
#pragma unroll
      for (int c = 0; c < 4; ++c) {
        int f4 = c0 + c * 4;
        float4 v = reinterpret_cast<const float4*>(src)[f4];
        *reinterpret_cast<float4*>(&Xs[rr][4 * f4]) = v;
      }
    } else {
#pragma unroll
      for (int c = 0; c < 4; ++c) {
        int f4 = c0 + c * 4;
        *reinterpret_cast<float4*>(&Xs[rr][4 * f4]) = float4{0.f, 0.f, 0.f, 0.f};
      }
    }
  }
  __syncthreads();

  int hg = t & 15;   // h0 = 4*hg
  int rg = t >> 4;   // r0 = 4*rg
  float acc[4][4] = {};
#pragma unroll
  for (int i = 0; i < 16; ++i) {  // f0 = 4*i
    float4 xr[4], wv[4];
#pragma unroll
    for (int j = 0; j < 4; ++j)
      xr[j] = *reinterpret_cast<const float4*>(&Xs[4 * rg + j][4 * i]);
#pragma unroll
    for (int k = 0; k < 4; ++k)
      wv[k] = *reinterpret_cast<const float4*>(&Wt[4 * i + k][4 * hg]);
#pragma unroll
    for (int j = 0; j < 4; ++j) {
      const float* xj = (const float*)&xr[j];
#pragma unroll
      for (int k = 0; k < 4; ++k) {
        const float* wk = (const float*)&wv[k];
        acc[j][0] = fmaf(xj[k], wk[0], acc[j][0]);
        acc[j][1] = fmaf(xj[k], wk[1], acc[j][1]);
        acc[j][2] = fmaf(xj[k], wk[2], acc[j][2]);
        acc[j][3] = fmaf(xj[k], wk[3], acc[j][3]);
      }
    }
  }
#pragma unroll
  for (int j = 0; j < 4; ++j) {
    int r = 4 * rg + j;
    if (r < nrows) {
      float4 o = {acc[j][0], acc[j][1], acc[j][2], acc[j][3]};
      reinterpret_cast<float4*>(&m[(size_t)(row0 + r) * 64])[hg] = o;
    }
  }
}

// Pull aggregation: block per dst node n, threads = (b,h) = BS*64.
// acc = self-loop + sum_{incoming e} m[src_e]*dinv[src]*dinv[n]
// val = relu(acc + bias); hout = val; q[n,b] (+)= sum_h val*fcw[h*L+layer]
__global__ void agg_kernel(const float* __restrict__ m, const float* __restrict__ dinv,
                           const float* __restrict__ bias, const int* __restrict__ row_start,
                           const int* __restrict__ csr, float* __restrict__ hout,
                           float* __restrict__ q, const float* __restrict__ fcw,
                           int layer, int L, int BS) {
  int n = blockIdx.x;
  int t = threadIdx.x;  // BS*64
  int b = t >> 6, lane = t & 63;
  float dn = dinv[n];
  int base = n * BS * 64;
  float acc = m[base + t] * (dn * dn);  // self-loop
  int beg = row_start[n], end = row_start[n + 1];
  for (int i = beg; i < end; ++i) {
    int s = csr[i];
    float w = dinv[s] * dn;
    acc = fmaf(m[s * BS * 64 + t], w, acc);
  }
  float val = fmaxf(acc + bias[lane], 0.f);
  hout[base + t] = val;
  float qp = val * fcw[lane * L + layer];
#pragma unroll
  for (int o = 32; o > 0; o >>= 1) qp += __shfl_down(qp, o);
  if (lane == 0) {
    if (layer == 0) q[n * BS + b] = qp;
    else q[n * BS + b] += qp;
  }
}

__global__ void pathway_kernel(const int* __restrict__ row, const int* __restrict__ col,
                               const float* __restrict__ q, float* __restrict__ s_sum,
                               float* __restrict__ cntc, int R, int BS) {
  int idx = blockIdx.x * blockDim.x + threadIdx.x;
  if (idx >= R * BS) return;
  int r = idx / BS, b = idx - (idx / BS) * BS;
  int c = col[r], nd = row[r];
  atomicAdd(&s_sum[c * BS + b], q[nd * BS + b]);
  if (b == 0) atomicAdd(&cntc[c], 1.0f);
}

__global__ void head_kernel(const float* __restrict__ s_sum, const float* __restrict__ cntc,
                            const float* __restrict__ fcb, const float* __restrict__ l1w,
                            const float* __restrict__ l1b, const float* __restrict__ l2w,
                            const float* __restrict__ l2b, float* __restrict__ out,
                            int NCMT, int HFC, int NCLS, int BS) {
  int b = blockIdx.x;
  __shared__ float sbuf[400];
  __shared__ float z1[200];
  __shared__ float z2[8];
  int t = threadIdx.x;  // 256
  for (int c = t; c < NCMT; c += 256) {
    float cn = fmaxf(cntc[c], 1.0f);
    sbuf[c] = s_sum[c * BS + b] / cn + fcb[0];
  }
  __syncthreads();
  for (int j = t; j < HFC; j += 256) {
    float a = l1b[j];
    for (int c = 0; c < NCMT; ++c) a = fmaf(sbuf[c], l1w[j * NCMT + c], a);
    z1[j] = fmaxf(a, 0.f);
  }
  __syncthreads();
  if (t < NCLS) {
    float a = l2b[t];
    for (int j = 0; j < HFC; ++j) a = fmaf(z1[j], l2w[t * HFC + j], a);
    z2[t] = a;
  }
  __syncthreads();
  if (t == 0) {
    float mx = z2[0];
    for (int k = 1; k < NCLS; ++k) mx = fmaxf(mx, z2[k]);
    float se = 0.f;
    for (int k = 0; k < NCLS; ++k) se += expf(z2[k] - mx);
    float lse = mx + logf(se);
    for (int k = 0; k < NCLS; ++k) out[b * NCLS + k] = z2[k] - lse;
  }
}

extern "C" void kernel_launch(void* const* d_in, const int* in_sizes, int n_in,
                              void* d_out, int out_size, void* d_ws, size_t ws_size,
                              hipStream_t stream) {
  const float* x   = (const float*)d_in[0];
  const int*  ei   = (const int*)d_in[2];
  const int*  row  = (const int*)d_in[3];
  const int*  col  = (const int*)d_in[4];
  const float* W1  = (const float*)d_in[5];
  const float* b1  = (const float*)d_in[6];
  const float* W2  = (const float*)d_in[7];
  const float* b2  = (const float*)d_in[8];
  const float* W3  = (const float*)d_in[9];
  const float* b3  = (const float*)d_in[10];
  const float* fcw = (const float*)d_in[11];
  const float* fcb = (const float*)d_in[12];
  const float* l1w = (const float*)d_in[13];
  const float* l1b = (const float*)d_in[14];
  const float* l2w = (const float*)d_in[15];
  const float* l2b = (const float*)d_in[16];

  const int BS   = in_sizes[1];               // 8
  const int H    = in_sizes[6];               // 64
  const int F    = in_sizes[5] / H;           // 64
  const int N    = in_sizes[0] / (BS * F);    // 15135
  const int E    = in_sizes[2] / 2;           // 300000
  const int R    = in_sizes[3];               // 40000
  const int HFC  = in_sizes[14];              // 200
  const int NCMT = in_sizes[13] / HFC;        // 400
  const int NCLS = in_sizes[16];              // 2
  const int L    = in_sizes[11] / H;          // 3

  // workspace carve-out (256B aligned)
  char* p = (char*)d_ws;
  auto alloc = [&](size_t bytes) {
    void* r = (void*)p;
    p += (bytes + 255) & ~(size_t)255;
    return r;
  };
  int*   degi      = (int*)alloc((size_t)N * 4);
  int*   cursor    = (int*)alloc((size_t)N * 4);
  int*   row_start = (int*)alloc((size_t)(N + 1) * 4);
  int*   csr       = (int*)alloc((size_t)E * 4);
  float* dinv      = (float*)alloc((size_t)N * 4);
  float* q         = (float*)alloc((size_t)N * BS * 4);
  float* s_sum     = (float*)alloc((size_t)NCMT * BS * 4);
  float* cntc      = (float*)alloc((size_t)NCMT * 4);
  float* m         = (float*)alloc((size_t)N * BS * H * 4);
  float* hA        = (float*)alloc((size_t)N * BS * H * 4);
  float* hB        = (float*)alloc((size_t)N * BS * H * 4);

  hipMemsetAsync(degi, 0, (size_t)N * 4, stream);
  hipMemsetAsync(cursor, 0, (size_t)N * 4, stream);
  hipMemsetAsync(s_sum, 0, (size_t)NCMT * BS * 4, stream);
  hipMemsetAsync(cntc, 0, (size_t)NCMT * 4, stream);

  const int* e_src = ei;
  const int* e_dst = ei + E;

  count_kernel<<<(E + 255) / 256, 256, 0, stream>>>(e_dst, degi, E);
  prefix_kernel<<<1, 1024, 0, stream>>>(degi, row_start, N);
  fill_kernel<<<(E + 255) / 256, 256, 0, stream>>>(e_src, e_dst, row_start, cursor, csr, E);
  dinv_kernel<<<(N + 255) / 256, 256, 0, stream>>>(degi, dinv, N);

  int lin_grid = (N * BS + 63) / 64;
  int agg_threads = BS * 64;  // 512

  // layer 1 (reads x via transposed indexing)
  linear_kernel<true><<<lin_grid, 256, 0, stream>>>(x, W1, m, N, BS);
  agg_kernel<<<N, agg_threads, 0, stream>>>(m, dinv, b1, row_start, csr, hA, q, fcw, 0, L, BS);
  // layer 2
  linear_kernel<false><<<lin_grid, 256, 0, stream>>>(hA, W2, m, N, BS);
  agg_kernel<<<N, agg_threads, 0, stream>>>(m, dinv, b2, row_start, csr, hB, q, fcw, 1, L, BS);
  // layer 3 (hA is dead, reuse it)
  linear_kernel<false><<<lin_grid, 256, 0, stream>>>(hB, W3, m, N, BS);
  agg_kernel<<<N, agg_threads, 0, stream>>>(m, dinv, b3, row_start, csr, hA, q, fcw, 2, L, BS);

  pathway_kernel<<<((size_t)R * BS + 255) / 256, 256, 0, stream>>>(row, col, q, s_sum, cntc, R, BS);
  head_kernel<<<BS, 256, 0, stream>>>(s_sum, cntc, fcb, l1w, l1b, l2w, l2b,
                                      (float*)d_out, NCMT, HFC, NCLS, BS);
}

// Round 4
// 1988.233 us; speedup vs baseline: 1.0368x; 1.0368x over previous
//
#include <hip/hip_runtime.h>

// ---------------------------------------------------------------------------
// GCNModelWPathways: 3-layer GCN (N nodes, BS=8 batch, H=64) + committee
// pathway pooling + 2-layer MLP head + log_softmax.
//
// Decomposition:
//   1. degree count + CSR build (by dst) + dinv = rsqrt(deg+1)
//   2. per layer: register-tiled linear GEMM (named-register microkernel —
//      NO local arrays: rule #20, arrays with taken addresses land in
//      scratch and cost ~1.6 GB of TCC traffic per dispatch), then
//      pull-aggregate (block-per-node, thread=(b,h)), fused ReLU+bias and
//      fused fc_w projection into q[N,BS] (mean/linear commute).
//   3. pathway scatter: s_sum[c,b] += q[row[r],b] (atomics, tiny dst buffer)
//   4. head: per-b MLP 400->200->2 + log_softmax.
// ---------------------------------------------------------------------------

__global__ void count_kernel(const int* __restrict__ dst, int* __restrict__ degi, int E) {
  int e = blockIdx.x * blockDim.x + threadIdx.x;
  if (e < E) atomicAdd(&degi[dst[e]], 1);
}

// single-block exclusive prefix sum over counts[0..n) -> row_start[0..n]
__global__ void prefix_kernel(const int* __restrict__ counts, int* __restrict__ row_start, int n) {
  __shared__ int sums[1024];
  int t = threadIdx.x;
  int chunk = (n + 1023) >> 10;
  int beg = t * chunk;
  int end = min(beg + chunk, n);
  int s = 0;
  for (int i = beg; i < end; ++i) s += counts[i];
  sums[t] = s;
  __syncthreads();
  for (int d = 1; d < 1024; d <<= 1) {
    int v = (t >= d) ? sums[t - d] : 0;
    __syncthreads();
    sums[t] += v;
    __syncthreads();
  }
  int off = (t == 0) ? 0 : sums[t - 1];
  for (int i = beg; i < end; ++i) { row_start[i] = off; off += counts[i]; }
  if (end == n) row_start[n] = off;  // all such threads write the total
}

__global__ void fill_kernel(const int* __restrict__ src, const int* __restrict__ dst,
                            const int* __restrict__ row_start, int* __restrict__ cursor,
                            int* __restrict__ csr, int E) {
  int e = blockIdx.x * blockDim.x + threadIdx.x;
  if (e < E) {
    int d = dst[e];
    int pos = atomicAdd(&cursor[d], 1);
    csr[row_start[d] + pos] = src[e];
  }
}

__global__ void dinv_kernel(const int* __restrict__ degi, float* __restrict__ dinv, int N) {
  int n = blockIdx.x * blockDim.x + threadIdx.x;
  if (n < N) dinv[n] = rsqrtf((float)(degi[n] + 1));  // +1: self-loop
}

// Register-tiled linear: m[r][h] = sum_f X[r][f] * W[h][f], rows = N*BS.
// Block: 64 rows x 64 h, 256 threads, each computes a 4x4 tile held in
// NAMED float4 registers (acc0..acc3) — no local arrays (scratch hazard).
// LDS rows padded to 68 floats -> every ds_read_b128 is <=2-way (free).
// FROM_X: input is x with layout [BS, N, F] (transpose folded into gather).
template <bool FROM_X>
__global__ void linear_kernel(const float* __restrict__ hin, const float* __restrict__ W,
                              float* __restrict__ m, int N, int BS) {
  __shared__ __align__(16) float Xs[64][68];
  __shared__ __align__(16) float Wt[64][68];  // Wt[f][h]
  int t = threadIdx.x;
  int rows_total = N * BS;
  int row0 = blockIdx.x * 64;
  int nrows = min(64, rows_total - row0);

  // stage W transposed (coalesced read, scattered LDS write; once per block)
  for (int i = t; i < 4096; i += 256) {
    int h = i >> 6, f = i & 63;
    Wt[f][h] = W[i];
  }
  // stage X tile: 4 threads per row, each covers 4 float4s (stride 4)
  {
    int rr = t >> 2;   // 0..63
    int c0 = t & 3;
    const float* src = nullptr;
    bool valid = rr < nrows;
    if (valid) {
      int g = row0 + rr;
      if (FROM_X) { int n = g / BS, b = g - n * BS; src = hin + ((size_t)b * N + n) * 64; }
      else        { src = hin + (size_t)g * 64; }
    }
#pragma unroll
    for (int c = 0; c < 4; ++c) {
      int f4 = c0 + c * 4;
      float4 v = valid ? reinterpret_cast<const float4*>(src)[f4]
                       : float4{0.f, 0.f, 0.f, 0.f};
      *reinterpret_cast<float4*>(&Xs[rr][4 * f4]) = v;
    }
  }
  __syncthreads();

  int hg = t & 15;   // h0 = 4*hg
  int rg = t >> 4;   // r0 = 4*rg
  int r0 = 4 * rg;

  float4 acc0 = {0.f, 0.f, 0.f, 0.f};
  float4 acc1 = {0.f, 0.f, 0.f, 0.f};
  float4 acc2 = {0.f, 0.f, 0.f, 0.f};
  float4 acc3 = {0.f, 0.f, 0.f, 0.f};

// NOTE: macro params must NOT be named x/y/z/w — member tokens would be
// substituted (round-3 compile failure).
#define FMA4(A, S, V)            \
  A.x = fmaf((S), (V).x, A.x);   \
  A.y = fmaf((S), (V).y, A.y);   \
  A.z = fmaf((S), (V).z, A.z);   \
  A.w = fmaf((S), (V).w, A.w);

#pragma unroll
  for (int i = 0; i < 16; ++i) {  // f0 = 4*i
    float4 xr0 = *reinterpret_cast<const float4*>(&Xs[r0 + 0][4 * i]);
    float4 xr1 = *reinterpret_cast<const float4*>(&Xs[r0 + 1][4 * i]);
    float4 xr2 = *reinterpret_cast<const float4*>(&Xs[r0 + 2][4 * i]);
    float4 xr3 = *reinterpret_cast<const float4*>(&Xs[r0 + 3][4 * i]);
    float4 wv0 = *reinterpret_cast<const float4*>(&Wt[4 * i + 0][4 * hg]);
    float4 wv1 = *reinterpret_cast<const float4*>(&Wt[4 * i + 1][4 * hg]);
    float4 wv2 = *reinterpret_cast<const float4*>(&Wt[4 * i + 2][4 * hg]);
    float4 wv3 = *reinterpret_cast<const float4*>(&Wt[4 * i + 3][4 * hg]);
    FMA4(acc0, xr0.x, wv0); FMA4(acc0, xr0.y, wv1); FMA4(acc0, xr0.z, wv2); FMA4(acc0, xr0.w, wv3);
    FMA4(acc1, xr1.x, wv0); FMA4(acc1, xr1.y, wv1); FMA4(acc1, xr1.z, wv2); FMA4(acc1, xr1.w, wv3);
    FMA4(acc2, xr2.x, wv0); FMA4(acc2, xr2.y, wv1); FMA4(acc2, xr2.z, wv2); FMA4(acc2, xr2.w, wv3);
    FMA4(acc3, xr3.x, wv0); FMA4(acc3, xr3.y, wv1); FMA4(acc3, xr3.z, wv2); FMA4(acc3, xr3.w, wv3);
  }
#undef FMA4

  if (r0 + 0 < nrows) reinterpret_cast<float4*>(&m[(size_t)(row0 + r0 + 0) * 64])[hg] = acc0;
  if (r0 + 1 < nrows) reinterpret_cast<float4*>(&m[(size_t)(row0 + r0 + 1) * 64])[hg] = acc1;
  if (r0 + 2 < nrows) reinterpret_cast<float4*>(&m[(size_t)(row0 + r0 + 2) * 64])[hg] = acc2;
  if (r0 + 3 < nrows) reinterpret_cast<float4*>(&m[(size_t)(row0 + r0 + 3) * 64])[hg] = acc3;
}

// Pull aggregation: block per dst node n, threads = (b,h) = BS*64.
// acc = self-loop + sum_{incoming e} m[src_e]*dinv[src]*dinv[n]
// val = relu(acc + bias); hout = val; q[n,b] (+)= sum_h val*fcw[h*L+layer]
__global__ void agg_kernel(const float* __restrict__ m, const float* __restrict__ dinv,
                           const float* __restrict__ bias, const int* __restrict__ row_start,
                           const int* __restrict__ csr, float* __restrict__ hout,
                           float* __restrict__ q, const float* __restrict__ fcw,
                           int layer, int L, int BS) {
  int n = blockIdx.x;
  int t = threadIdx.x;  // BS*64
  int b = t >> 6, lane = t & 63;
  float dn = dinv[n];
  int base = n * BS * 64;
  float acc = m[base + t] * (dn * dn);  // self-loop
  int beg = row_start[n], end = row_start[n + 1];
  for (int i = beg; i < end; ++i) {
    int s = csr[i];
    float w = dinv[s] * dn;
    acc = fmaf(m[s * BS * 64 + t], w, acc);
  }
  float val = fmaxf(acc + bias[lane], 0.f);
  hout[base + t] = val;
  float qp = val * fcw[lane * L + layer];
#pragma unroll
  for (int o = 32; o > 0; o >>= 1) qp += __shfl_down(qp, o);
  if (lane == 0) {
    if (layer == 0) q[n * BS + b] = qp;
    else q[n * BS + b] += qp;
  }
}

__global__ void pathway_kernel(const int* __restrict__ row, const int* __restrict__ col,
                               const float* __restrict__ q, float* __restrict__ s_sum,
                               float* __restrict__ cntc, int R, int BS) {
  int idx = blockIdx.x * blockDim.x + threadIdx.x;
  if (idx >= R * BS) return;
  int r = idx / BS, b = idx - (idx / BS) * BS;
  int c = col[r], nd = row[r];
  atomicAdd(&s_sum[c * BS + b], q[nd * BS + b]);
  if (b == 0) atomicAdd(&cntc[c], 1.0f);
}

__global__ void head_kernel(const float* __restrict__ s_sum, const float* __restrict__ cntc,
                            const float* __restrict__ fcb, const float* __restrict__ l1w,
                            const float* __restrict__ l1b, const float* __restrict__ l2w,
                            const float* __restrict__ l2b, float* __restrict__ out,
                            int NCMT, int HFC, int NCLS, int BS) {
  int b = blockIdx.x;
  __shared__ float sbuf[400];
  __shared__ float z1[200];
  __shared__ float z2[8];
  int t = threadIdx.x;  // 256
  for (int c = t; c < NCMT; c += 256) {
    float cn = fmaxf(cntc[c], 1.0f);
    sbuf[c] = s_sum[c * BS + b] / cn + fcb[0];
  }
  __syncthreads();
  for (int j = t; j < HFC; j += 256) {
    float a = l1b[j];
    for (int c = 0; c < NCMT; ++c) a = fmaf(sbuf[c], l1w[j * NCMT + c], a);
    z1[j] = fmaxf(a, 0.f);
  }
  __syncthreads();
  if (t < NCLS) {
    float a = l2b[t];
    for (int j = 0; j < HFC; ++j) a = fmaf(z1[j], l2w[t * HFC + j], a);
    z2[t] = a;
  }
  __syncthreads();
  if (t == 0) {
    float mx = z2[0];
    for (int k = 1; k < NCLS; ++k) mx = fmaxf(mx, z2[k]);
    float se = 0.f;
    for (int k = 0; k < NCLS; ++k) se += expf(z2[k] - mx);
    float lse = mx + logf(se);
    for (int k = 0; k < NCLS; ++k) out[b * NCLS + k] = z2[k] - lse;
  }
}

extern "C" void kernel_launch(void* const* d_in, const int* in_sizes, int n_in,
                              void* d_out, int out_size, void* d_ws, size_t ws_size,
                              hipStream_t stream) {
  const float* x   = (const float*)d_in[0];
  const int*  ei   = (const int*)d_in[2];
  const int*  row  = (const int*)d_in[3];
  const int*  col  = (const int*)d_in[4];
  const float* W1  = (const float*)d_in[5];
  const float* b1  = (const float*)d_in[6];
  const float* W2  = (const float*)d_in[7];
  const float* b2  = (const float*)d_in[8];
  const float* W3  = (const float*)d_in[9];
  const float* b3  = (const float*)d_in[10];
  const float* fcw = (const float*)d_in[11];
  const float* fcb = (const float*)d_in[12];
  const float* l1w = (const float*)d_in[13];
  const float* l1b = (const float*)d_in[14];
  const float* l2w = (const float*)d_in[15];
  const float* l2b = (const float*)d_in[16];

  const int BS   = in_sizes[1];               // 8
  const int H    = in_sizes[6];               // 64
  const int F    = in_sizes[5] / H;           // 64
  const int N    = in_sizes[0] / (BS * F);    // 15135
  const int E    = in_sizes[2] / 2;           // 300000
  const int R    = in_sizes[3];               // 40000
  const int HFC  = in_sizes[14];              // 200
  const int NCMT = in_sizes[13] / HFC;        // 400
  const int NCLS = in_sizes[16];              // 2
  const int L    = in_sizes[11] / H;          // 3

  // workspace carve-out (256B aligned)
  char* p = (char*)d_ws;
  auto alloc = [&](size_t bytes) {
    void* r = (void*)p;
    p += (bytes + 255) & ~(size_t)255;
    return r;
  };
  int*   degi      = (int*)alloc((size_t)N * 4);
  int*   cursor    = (int*)alloc((size_t)N * 4);
  int*   row_start = (int*)alloc((size_t)(N + 1) * 4);
  int*   csr       = (int*)alloc((size_t)E * 4);
  float* dinv      = (float*)alloc((size_t)N * 4);
  float* q         = (float*)alloc((size_t)N * BS * 4);
  float* s_sum     = (float*)alloc((size_t)NCMT * BS * 4);
  float* cntc      = (float*)alloc((size_t)NCMT * 4);
  float* m         = (float*)alloc((size_t)N * BS * H * 4);
  float* hA        = (float*)alloc((size_t)N * BS * H * 4);
  float* hB        = (float*)alloc((size_t)N * BS * H * 4);

  hipMemsetAsync(degi, 0, (size_t)N * 4, stream);
  hipMemsetAsync(cursor, 0, (size_t)N * 4, stream);
  hipMemsetAsync(s_sum, 0, (size_t)NCMT * BS * 4, stream);
  hipMemsetAsync(cntc, 0, (size_t)NCMT * 4, stream);

  const int* e_src = ei;
  const int* e_dst = ei + E;

  count_kernel<<<(E + 255) / 256, 256, 0, stream>>>(e_dst, degi, E);
  prefix_kernel<<<1, 1024, 0, stream>>>(degi, row_start, N);
  fill_kernel<<<(E + 255) / 256, 256, 0, stream>>>(e_src, e_dst, row_start, cursor, csr, E);
  dinv_kernel<<<(N + 255) / 256, 256, 0, stream>>>(degi, dinv, N);

  int lin_grid = (N * BS + 63) / 64;
  int agg_threads = BS * 64;  // 512

  // layer 1 (reads x via transposed indexing)
  linear_kernel<true><<<lin_grid, 256, 0, stream>>>(x, W1, m, N, BS);
  agg_kernel<<<N, agg_threads, 0, stream>>>(m, dinv, b1, row_start, csr, hA, q, fcw, 0, L, BS);
  // layer 2
  linear_kernel<false><<<lin_grid, 256, 0, stream>>>(hA, W2, m, N, BS);
  agg_kernel<<<N, agg_threads, 0, stream>>>(m, dinv, b2, row_start, csr, hB, q, fcw, 1, L, BS);
  // layer 3 (hA is dead, reuse it)
  linear_kernel<false><<<lin_grid, 256, 0, stream>>>(hB, W3, m, N, BS);
  agg_kernel<<<N, agg_threads, 0, stream>>>(m, dinv, b3, row_start, csr, hA, q, fcw, 2, L, BS);

  pathway_kernel<<<((size_t)R * BS + 255) / 256, 256, 0, stream>>>(row, col, q, s_sum, cntc, R, BS);
  head_kernel<<<BS, 256, 0, stream>>>(s_sum, cntc, fcb, l1w, l1b, l2w, l2b,
                                      (float*)d_out, NCMT, HFC, NCLS, BS);
}

// Round 5
// 668.247 us; speedup vs baseline: 3.0847x; 2.9753x over previous
//
#include <hip/hip_runtime.h>

// ---------------------------------------------------------------------------
// GCNModelWPathways: 3-layer GCN (N nodes, BS=8 batch, H=64) + committee
// pathway pooling + 2-layer MLP head + log_softmax.
//
// Decomposition:
//   1. degree count + CSR build (by dst) + dinv = rsqrt(deg+1)
//   2. per layer: register-tiled linear GEMM, then pull-aggregate
//      (block-per-node, thread=(b,h)), fused ReLU+bias and fused fc_w
//      projection into q[N,BS] (mean/linear commute).
//   3. pathway scatter: s_sum[c,b] += q[row[r],b] (atomics, tiny dst buffer)
//   4. head: per-b MLP 400->200->2 + log_softmax.
//
// R4 lesson: without __launch_bounds__, the backend targeted the 64-VGPR /
// 8-waves-per-SIMD occupancy tier and spilled the 4x4 register tile ->
// ~1.6 GB of scratch traffic per dispatch (WRITE_SIZE 22x the output size).
// __launch_bounds__(256, 1) releases the VGPR budget.
// ---------------------------------------------------------------------------

__global__ void count_kernel(const int* __restrict__ dst, int* __restrict__ degi, int E) {
  int e = blockIdx.x * blockDim.x + threadIdx.x;
  if (e < E) atomicAdd(&degi[dst[e]], 1);
}

// single-block exclusive prefix sum over counts[0..n) -> row_start[0..n]
__global__ void prefix_kernel(const int* __restrict__ counts, int* __restrict__ row_start, int n) {
  __shared__ int sums[1024];
  int t = threadIdx.x;
  int chunk = (n + 1023) >> 10;
  int beg = t * chunk;
  int end = min(beg + chunk, n);
  int s = 0;
  for (int i = beg; i < end; ++i) s += counts[i];
  sums[t] = s;
  __syncthreads();
  for (int d = 1; d < 1024; d <<= 1) {
    int v = (t >= d) ? sums[t - d] : 0;
    __syncthreads();
    sums[t] += v;
    __syncthreads();
  }
  int off = (t == 0) ? 0 : sums[t - 1];
  for (int i = beg; i < end; ++i) { row_start[i] = off; off += counts[i]; }
  if (end == n) row_start[n] = off;  // all such threads write the total
}

__global__ void fill_kernel(const int* __restrict__ src, const int* __restrict__ dst,
                            const int* __restrict__ row_start, int* __restrict__ cursor,
                            int* __restrict__ csr, int E) {
  int e = blockIdx.x * blockDim.x + threadIdx.x;
  if (e < E) {
    int d = dst[e];
    int pos = atomicAdd(&cursor[d], 1);
    csr[row_start[d] + pos] = src[e];
  }
}

__global__ void dinv_kernel(const int* __restrict__ degi, float* __restrict__ dinv, int N) {
  int n = blockIdx.x * blockDim.x + threadIdx.x;
  if (n < N) dinv[n] = rsqrtf((float)(degi[n] + 1));  // +1: self-loop
}

// Register-tiled linear: m[r][h] = sum_f X[r][f] * W[h][f], rows = N*BS.
// Block: 64 rows x 64 h, 256 threads, each computes a 4x4 tile in named
// float4 registers. LDS rows padded to 68 floats -> ds_read_b128 <=2-way.
// FROM_X: input is x with layout [BS, N, F] (transpose folded into gather).
template <bool FROM_X>
__global__ __launch_bounds__(256, 1)  // release VGPR budget; no 64-reg tier spills
void linear_kernel(const float* __restrict__ hin, const float* __restrict__ W,
                   float* __restrict__ m, int N, int BS) {
  __shared__ __align__(16) float Xs[64][68];
  __shared__ __align__(16) float Wt[64][68];  // Wt[f][h]
  int t = threadIdx.x;
  int rows_total = N * BS;
  int row0 = blockIdx.x * 64;
  int nrows = min(64, rows_total - row0);

  // stage W transposed (coalesced read, scattered LDS write; once per block)
  for (int i = t; i < 4096; i += 256) {
    int h = i >> 6, f = i & 63;
    Wt[f][h] = W[i];
  }
  // stage X tile: 4 threads per row, each covers 4 float4s (stride 4)
  {
    int rr = t >> 2;   // 0..63
    int c0 = t & 3;
    const float* src = nullptr;
    bool valid = rr < nrows;
    if (valid) {
      int g = row0 + rr;
      if (FROM_X) { int n = g / BS, b = g - n * BS; src = hin + ((size_t)b * N + n) * 64; }
      else        { src = hin + (size_t)g * 64; }
    }
#pragma unroll
    for (int c = 0; c < 4; ++c) {
      int f4 = c0 + c * 4;
      float4 v = valid ? reinterpret_cast<const float4*>(src)[f4]
                       : float4{0.f, 0.f, 0.f, 0.f};
      *reinterpret_cast<float4*>(&Xs[rr][4 * f4]) = v;
    }
  }
  __syncthreads();

  int hg = t & 15;   // h0 = 4*hg
  int rg = t >> 4;   // r0 = 4*rg
  int r0 = 4 * rg;

  float4 acc0 = {0.f, 0.f, 0.f, 0.f};
  float4 acc1 = {0.f, 0.f, 0.f, 0.f};
  float4 acc2 = {0.f, 0.f, 0.f, 0.f};
  float4 acc3 = {0.f, 0.f, 0.f, 0.f};

// NOTE: macro params must NOT be named x/y/z/w (round-3 compile failure).
#define FMA4(A, S, V)            \
  A.x = fmaf((S), (V).x, A.x);   \
  A.y = fmaf((S), (V).y, A.y);   \
  A.z = fmaf((S), (V).z, A.z);   \
  A.w = fmaf((S), (V).w, A.w);

#pragma unroll
  for (int i = 0; i < 16; ++i) {  // f0 = 4*i
    float4 xr0 = *reinterpret_cast<const float4*>(&Xs[r0 + 0][4 * i]);
    float4 xr1 = *reinterpret_cast<const float4*>(&Xs[r0 + 1][4 * i]);
    float4 xr2 = *reinterpret_cast<const float4*>(&Xs[r0 + 2][4 * i]);
    float4 xr3 = *reinterpret_cast<const float4*>(&Xs[r0 + 3][4 * i]);
    float4 wv0 = *reinterpret_cast<const float4*>(&Wt[4 * i + 0][4 * hg]);
    float4 wv1 = *reinterpret_cast<const float4*>(&Wt[4 * i + 1][4 * hg]);
    float4 wv2 = *reinterpret_cast<const float4*>(&Wt[4 * i + 2][4 * hg]);
    float4 wv3 = *reinterpret_cast<const float4*>(&Wt[4 * i + 3][4 * hg]);
    FMA4(acc0, xr0.x, wv0); FMA4(acc0, xr0.y, wv1); FMA4(acc0, xr0.z, wv2); FMA4(acc0, xr0.w, wv3);
    FMA4(acc1, xr1.x, wv0); FMA4(acc1, xr1.y, wv1); FMA4(acc1, xr1.z, wv2); FMA4(acc1, xr1.w, wv3);
    FMA4(acc2, xr2.x, wv0); FMA4(acc2, xr2.y, wv1); FMA4(acc2, xr2.z, wv2); FMA4(acc2, xr2.w, wv3);
    FMA4(acc3, xr3.x, wv0); FMA4(acc3, xr3.y, wv1); FMA4(acc3, xr3.z, wv2); FMA4(acc3, xr3.w, wv3);
  }
#undef FMA4

  if (r0 + 0 < nrows) reinterpret_cast<float4*>(&m[(size_t)(row0 + r0 + 0) * 64])[hg] = acc0;
  if (r0 + 1 < nrows) reinterpret_cast<float4*>(&m[(size_t)(row0 + r0 + 1) * 64])[hg] = acc1;
  if (r0 + 2 < nrows) reinterpret_cast<float4*>(&m[(size_t)(row0 + r0 + 2) * 64])[hg] = acc2;
  if (r0 + 3 < nrows) reinterpret_cast<float4*>(&m[(size_t)(row0 + r0 + 3) * 64])[hg] = acc3;
}

// Pull aggregation: block per dst node n, threads = (b,h) = BS*64.
// acc = self-loop + sum_{incoming e} m[src_e]*dinv[src]*dinv[n]
// val = relu(acc + bias); hout = val; q[n,b] (+)= sum_h val*fcw[h*L+layer]
__global__ void agg_kernel(const float* __restrict__ m, const float* __restrict__ dinv,
                           const float* __restrict__ bias, const int* __restrict__ row_start,
                           const int* __restrict__ csr, float* __restrict__ hout,
                           float* __restrict__ q, const float* __restrict__ fcw,
                           int layer, int L, int BS) {
  int n = blockIdx.x;
  int t = threadIdx.x;  // BS*64
  int b = t >> 6, lane = t & 63;
  float dn = dinv[n];
  int base = n * BS * 64;
  float acc = m[base + t] * (dn * dn);  // self-loop
  int beg = row_start[n], end = row_start[n + 1];
  for (int i = beg; i < end; ++i) {
    int s = csr[i];
    float w = dinv[s] * dn;
    acc = fmaf(m[s * BS * 64 + t], w, acc);
  }
  float val = fmaxf(acc + bias[lane], 0.f);
  hout[base + t] = val;
  float qp = val * fcw[lane * L + layer];
#pragma unroll
  for (int o = 32; o > 0; o >>= 1) qp += __shfl_down(qp, o);
  if (lane == 0) {
    if (layer == 0) q[n * BS + b] = qp;
    else q[n * BS + b] += qp;
  }
}

__global__ void pathway_kernel(const int* __restrict__ row, const int* __restrict__ col,
                               const float* __restrict__ q, float* __restrict__ s_sum,
                               float* __restrict__ cntc, int R, int BS) {
  int idx = blockIdx.x * blockDim.x + threadIdx.x;
  if (idx >= R * BS) return;
  int r = idx / BS, b = idx - (idx / BS) * BS;
  int c = col[r], nd = row[r];
  atomicAdd(&s_sum[c * BS + b], q[nd * BS + b]);
  if (b == 0) atomicAdd(&cntc[c], 1.0f);
}

__global__ void head_kernel(const float* __restrict__ s_sum, const float* __restrict__ cntc,
                            const float* __restrict__ fcb, const float* __restrict__ l1w,
                            const float* __restrict__ l1b, const float* __restrict__ l2w,
                            const float* __restrict__ l2b, float* __restrict__ out,
                            int NCMT, int HFC, int NCLS, int BS) {
  int b = blockIdx.x;
  __shared__ float sbuf[400];
  __shared__ float z1[200];
  __shared__ float z2[8];
  int t = threadIdx.x;  // 256
  for (int c = t; c < NCMT; c += 256) {
    float cn = fmaxf(cntc[c], 1.0f);
    sbuf[c] = s_sum[c * BS + b] / cn + fcb[0];
  }
  __syncthreads();
  for (int j = t; j < HFC; j += 256) {
    float a = l1b[j];
    for (int c = 0; c < NCMT; ++c) a = fmaf(sbuf[c], l1w[j * NCMT + c], a);
    z1[j] = fmaxf(a, 0.f);
  }
  __syncthreads();
  if (t < NCLS) {
    float a = l2b[t];
    for (int j = 0; j < HFC; ++j) a = fmaf(z1[j], l2w[t * HFC + j], a);
    z2[t] = a;
  }
  __syncthreads();
  if (t == 0) {
    float mx = z2[0];
    for (int k = 1; k < NCLS; ++k) mx = fmaxf(mx, z2[k]);
    float se = 0.f;
    for (int k = 0; k < NCLS; ++k) se += expf(z2[k] - mx);
    float lse = mx + logf(se);
    for (int k = 0; k < NCLS; ++k) out[b * NCLS + k] = z2[k] - lse;
  }
}

extern "C" void kernel_launch(void* const* d_in, const int* in_sizes, int n_in,
                              void* d_out, int out_size, void* d_ws, size_t ws_size,
                              hipStream_t stream) {
  const float* x   = (const float*)d_in[0];
  const int*  ei   = (const int*)d_in[2];
  const int*  row  = (const int*)d_in[3];
  const int*  col  = (const int*)d_in[4];
  const float* W1  = (const float*)d_in[5];
  const float* b1  = (const float*)d_in[6];
  const float* W2  = (const float*)d_in[7];
  const float* b2  = (const float*)d_in[8];
  const float* W3  = (const float*)d_in[9];
  const float* b3  = (const float*)d_in[10];
  const float* fcw = (const float*)d_in[11];
  const float* fcb = (const float*)d_in[12];
  const float* l1w = (const float*)d_in[13];
  const float* l1b = (const float*)d_in[14];
  const float* l2w = (const float*)d_in[15];
  const float* l2b = (const float*)d_in[16];

  const int BS   = in_sizes[1];               // 8
  const int H    = in_sizes[6];               // 64
  const int F    = in_sizes[5] / H;           // 64
  const int N    = in_sizes[0] / (BS * F);    // 15135
  const int E    = in_sizes[2] / 2;           // 300000
  const int R    = in_sizes[3];               // 40000
  const int HFC  = in_sizes[14];              // 200
  const int NCMT = in_sizes[13] / HFC;        // 400
  const int NCLS = in_sizes[16];              // 2
  const int L    = in_sizes[11] / H;          // 3

  // workspace carve-out (256B aligned)
  char* p = (char*)d_ws;
  auto alloc = [&](size_t bytes) {
    void* r = (void*)p;
    p += (bytes + 255) & ~(size_t)255;
    return r;
  };
  int*   degi      = (int*)alloc((size_t)N * 4);
  int*   cursor    = (int*)alloc((size_t)N * 4);
  int*   row_start = (int*)alloc((size_t)(N + 1) * 4);
  int*   csr       = (int*)alloc((size_t)E * 4);
  float* dinv      = (float*)alloc((size_t)N * 4);
  float* q         = (float*)alloc((size_t)N * BS * 4);
  float* s_sum     = (float*)alloc((size_t)NCMT * BS * 4);
  float* cntc      = (float*)alloc((size_t)NCMT * 4);
  float* m         = (float*)alloc((size_t)N * BS * H * 4);
  float* hA        = (float*)alloc((size_t)N * BS * H * 4);
  float* hB        = (float*)alloc((size_t)N * BS * H * 4);

  hipMemsetAsync(degi, 0, (size_t)N * 4, stream);
  hipMemsetAsync(cursor, 0, (size_t)N * 4, stream);
  hipMemsetAsync(s_sum, 0, (size_t)NCMT * BS * 4, stream);
  hipMemsetAsync(cntc, 0, (size_t)NCMT * 4, stream);

  const int* e_src = ei;
  const int* e_dst = ei + E;

  count_kernel<<<(E + 255) / 256, 256, 0, stream>>>(e_dst, degi, E);
  prefix_kernel<<<1, 1024, 0, stream>>>(degi, row_start, N);
  fill_kernel<<<(E + 255) / 256, 256, 0, stream>>>(e_src, e_dst, row_start, cursor, csr, E);
  dinv_kernel<<<(N + 255) / 256, 256, 0, stream>>>(degi, dinv, N);

  int lin_grid = (N * BS + 63) / 64;
  int agg_threads = BS * 64;  // 512

  // layer 1 (reads x via transposed indexing)
  linear_kernel<true><<<lin_grid, 256, 0, stream>>>(x, W1, m, N, BS);
  agg_kernel<<<N, agg_threads, 0, stream>>>(m, dinv, b1, row_start, csr, hA, q, fcw, 0, L, BS);
  // layer 2
  linear_kernel<false><<<lin_grid, 256, 0, stream>>>(hA, W2, m, N, BS);
  agg_kernel<<<N, agg_threads, 0, stream>>>(m, dinv, b2, row_start, csr, hB, q, fcw, 1, L, BS);
  // layer 3 (hA is dead, reuse it)
  linear_kernel<false><<<lin_grid, 256, 0, stream>>>(hB, W3, m, N, BS);
  agg_kernel<<<N, agg_threads, 0, stream>>>(m, dinv, b3, row_start, csr, hA, q, fcw, 2, L, BS);

  pathway_kernel<<<((size_t)R * BS + 255) / 256, 256, 0, stream>>>(row, col, q, s_sum, cntc, R, BS);
  head_kernel<<<BS, 256, 0, stream>>>(s_sum, cntc, fcb, l1w, l1b, l2w, l2b,
                                      (float*)d_out, NCMT, HFC, NCLS, BS);
}

// Round 6
// 612.794 us; speedup vs baseline: 3.3638x; 1.0905x over previous
//
#include <hip/hip_runtime.h>

// ---------------------------------------------------------------------------
// GCNModelWPathways: 3-layer GCN (N nodes, BS=8 batch, H=64) + committee
// pathway pooling + 2-layer MLP head + log_softmax.
//
// Layout strategy (R5): all node features stored [b][n][h]. One b-slice =
// N*64*4B = 3.87 MB -> fits one XCD's 4 MB L2. Both linear and agg map
// b = blockIdx % 8; with round-robin blockIdx->XCD dispatch each XCD owns
// one batch slice for the whole layer pipeline, so the random edge gather
// hits its own L2 instead of streaming 280 MB from L3 per layer.
// (Mapping is a perf heuristic only — correctness never depends on it.)
//
// R4 lesson kept: __launch_bounds__(256,1) on linear — without it the
// backend targets the 64-VGPR tier and spills the 4x4 tile (~1.6 GB scratch).
// ---------------------------------------------------------------------------

__global__ void count_kernel(const int* __restrict__ dst, int* __restrict__ degi, int E) {
  int e = blockIdx.x * blockDim.x + threadIdx.x;
  if (e < E) atomicAdd(&degi[dst[e]], 1);
}

// single-block exclusive prefix sum over counts[0..n) -> row_start[0..n]
__global__ void prefix_kernel(const int* __restrict__ counts, int* __restrict__ row_start, int n) {
  __shared__ int sums[1024];
  int t = threadIdx.x;
  int chunk = (n + 1023) >> 10;
  int beg = t * chunk;
  int end = min(beg + chunk, n);
  int s = 0;
  for (int i = beg; i < end; ++i) s += counts[i];
  sums[t] = s;
  __syncthreads();
  for (int d = 1; d < 1024; d <<= 1) {
    int v = (t >= d) ? sums[t - d] : 0;
    __syncthreads();
    sums[t] += v;
    __syncthreads();
  }
  int off = (t == 0) ? 0 : sums[t - 1];
  for (int i = beg; i < end; ++i) { row_start[i] = off; off += counts[i]; }
  if (end == n) row_start[n] = off;  // all such threads write the total
}

__global__ void fill_kernel(const int* __restrict__ src, const int* __restrict__ dst,
                            const int* __restrict__ row_start, int* __restrict__ cursor,
                            int* __restrict__ csr, int E) {
  int e = blockIdx.x * blockDim.x + threadIdx.x;
  if (e < E) {
    int d = dst[e];
    int pos = atomicAdd(&cursor[d], 1);
    csr[row_start[d] + pos] = src[e];
  }
}

__global__ void dinv_kernel(const int* __restrict__ degi, float* __restrict__ dinv, int N) {
  int n = blockIdx.x * blockDim.x + threadIdx.x;
  if (n < N) dinv[n] = rsqrtf((float)(degi[n] + 1));  // +1: self-loop
}

// Register-tiled linear on one b-slice: m[b][r][h] = sum_f H[b][r][f]*W[h][f].
// Grid = ceil(N/64) * BS blocks; b = blockIdx % BS (XCD-aligned), 256 threads,
// 64 rows x 64 h per block, 4x4 tile per thread in named float4 registers.
// x is natively [b][n][f], so layer 1 uses identical indexing (no transpose).
__global__ __launch_bounds__(256, 1)  // release VGPR budget; no 64-reg tier spills
void linear_kernel(const float* __restrict__ hin, const float* __restrict__ W,
                   float* __restrict__ m, int N, int BS) {
  __shared__ __align__(16) float Xs[64][68];
  __shared__ __align__(16) float Wt[64][68];  // Wt[f][h]
  int t = threadIdx.x;
  int b = blockIdx.x % BS;
  int chunk = blockIdx.x / BS;
  int row0 = chunk * 64;                 // node index within slice
  int nrows = min(64, N - row0);
  size_t sbase = ((size_t)b * N + row0) * 64;

  // stage W transposed (coalesced read, scattered LDS write; once per block)
  for (int i = t; i < 4096; i += 256) {
    int h = i >> 6, f = i & 63;
    Wt[f][h] = W[i];
  }
  // stage X tile: 4 threads per row, each covers 4 float4s (stride 4)
  {
    int rr = t >> 2;   // 0..63
    int c0 = t & 3;
    bool valid = rr < nrows;
    const float* src = hin + sbase + (size_t)rr * 64;
#pragma unroll
    for (int c = 0; c < 4; ++c) {
      int f4 = c0 + c * 4;
      float4 v = valid ? reinterpret_cast<const float4*>(src)[f4]
                       : float4{0.f, 0.f, 0.f, 0.f};
      *reinterpret_cast<float4*>(&Xs[rr][4 * f4]) = v;
    }
  }
  __syncthreads();

  int hg = t & 15;   // h0 = 4*hg
  int rg = t >> 4;   // r0 = 4*rg
  int r0 = 4 * rg;

  float4 acc0 = {0.f, 0.f, 0.f, 0.f};
  float4 acc1 = {0.f, 0.f, 0.f, 0.f};
  float4 acc2 = {0.f, 0.f, 0.f, 0.f};
  float4 acc3 = {0.f, 0.f, 0.f, 0.f};

// NOTE: macro params must NOT be named x/y/z/w (round-3 compile failure).
#define FMA4(A, S, V)            \
  A.x = fmaf((S), (V).x, A.x);   \
  A.y = fmaf((S), (V).y, A.y);   \
  A.z = fmaf((S), (V).z, A.z);   \
  A.w = fmaf((S), (V).w, A.w);

#pragma unroll
  for (int i = 0; i < 16; ++i) {  // f0 = 4*i
    float4 xr0 = *reinterpret_cast<const float4*>(&Xs[r0 + 0][4 * i]);
    float4 xr1 = *reinterpret_cast<const float4*>(&Xs[r0 + 1][4 * i]);
    float4 xr2 = *reinterpret_cast<const float4*>(&Xs[r0 + 2][4 * i]);
    float4 xr3 = *reinterpret_cast<const float4*>(&Xs[r0 + 3][4 * i]);
    float4 wv0 = *reinterpret_cast<const float4*>(&Wt[4 * i + 0][4 * hg]);
    float4 wv1 = *reinterpret_cast<const float4*>(&Wt[4 * i + 1][4 * hg]);
    float4 wv2 = *reinterpret_cast<const float4*>(&Wt[4 * i + 2][4 * hg]);
    float4 wv3 = *reinterpret_cast<const float4*>(&Wt[4 * i + 3][4 * hg]);
    FMA4(acc0, xr0.x, wv0); FMA4(acc0, xr0.y, wv1); FMA4(acc0, xr0.z, wv2); FMA4(acc0, xr0.w, wv3);
    FMA4(acc1, xr1.x, wv0); FMA4(acc1, xr1.y, wv1); FMA4(acc1, xr1.z, wv2); FMA4(acc1, xr1.w, wv3);
    FMA4(acc2, xr2.x, wv0); FMA4(acc2, xr2.y, wv1); FMA4(acc2, xr2.z, wv2); FMA4(acc2, xr2.w, wv3);
    FMA4(acc3, xr3.x, wv0); FMA4(acc3, xr3.y, wv1); FMA4(acc3, xr3.z, wv2); FMA4(acc3, xr3.w, wv3);
  }
#undef FMA4

  if (r0 + 0 < nrows) reinterpret_cast<float4*>(&m[sbase + (size_t)(r0 + 0) * 64])[hg] = acc0;
  if (r0 + 1 < nrows) reinterpret_cast<float4*>(&m[sbase + (size_t)(r0 + 1) * 64])[hg] = acc1;
  if (r0 + 2 < nrows) reinterpret_cast<float4*>(&m[sbase + (size_t)(r0 + 2) * 64])[hg] = acc2;
  if (r0 + 3 < nrows) reinterpret_cast<float4*>(&m[sbase + (size_t)(r0 + 3) * 64])[hg] = acc3;
}

// Pull aggregation on one b-slice. Grid = ceil(N/8) * BS; b = blockIdx % BS
// (XCD-aligned). Block = 512 threads = 8 waves; each wave owns one node,
// lane = h. Per edge the wave reads a contiguous 256B row from the L2-resident
// slice. 2-way edge unroll for ILP. WRITE_H=false on the last layer (hout dead).
template <bool WRITE_H>
__global__ void agg_kernel(const float* __restrict__ m, const float* __restrict__ dinv,
                           const float* __restrict__ bias, const int* __restrict__ row_start,
                           const int* __restrict__ csr, float* __restrict__ hout,
                           float* __restrict__ q, const float* __restrict__ fcw,
                           int layer, int L, int N, int BS) {
  int b = blockIdx.x % BS;
  int chunk = blockIdx.x / BS;
  int w = threadIdx.x >> 6, lane = threadIdx.x & 63;
  int n = chunk * 8 + w;
  if (n >= N) return;
  size_t bN = (size_t)b * N;
  const float* mb = m + bN * 64;
  float dn = dinv[n];
  float acc = mb[(size_t)n * 64 + lane] * (dn * dn);  // self-loop
  float acc1 = 0.f;
  int beg = row_start[n], end = row_start[n + 1];
  int i = beg;
  for (; i + 1 < end; i += 2) {
    int s0 = csr[i], s1 = csr[i + 1];
    float w0 = dinv[s0] * dn, w1 = dinv[s1] * dn;
    acc  = fmaf(mb[(size_t)s0 * 64 + lane], w0, acc);
    acc1 = fmaf(mb[(size_t)s1 * 64 + lane], w1, acc1);
  }
  if (i < end) {
    int s = csr[i];
    acc = fmaf(mb[(size_t)s * 64 + lane], dinv[s] * dn, acc);
  }
  acc += acc1;
  float val = fmaxf(acc + bias[lane], 0.f);
  if (WRITE_H) hout[bN * 64 + (size_t)n * 64 + lane] = val;
  float qp = val * fcw[lane * L + layer];
#pragma unroll
  for (int o = 32; o > 0; o >>= 1) qp += __shfl_down(qp, o);
  if (lane == 0) {
    if (layer == 0) q[bN + n] = qp;
    else q[bN + n] += qp;
  }
}

__global__ void pathway_kernel(const int* __restrict__ row, const int* __restrict__ col,
                               const float* __restrict__ q, float* __restrict__ s_sum,
                               float* __restrict__ cntc, int R, int N, int BS) {
  int idx = blockIdx.x * blockDim.x + threadIdx.x;
  if (idx >= R * BS) return;
  int r = idx / BS, b = idx - (idx / BS) * BS;
  int c = col[r], nd = row[r];
  atomicAdd(&s_sum[c * BS + b], q[(size_t)b * N + nd]);
  if (b == 0) atomicAdd(&cntc[c], 1.0f);
}

__global__ void head_kernel(const float* __restrict__ s_sum, const float* __restrict__ cntc,
                            const float* __restrict__ fcb, const float* __restrict__ l1w,
                            const float* __restrict__ l1b, const float* __restrict__ l2w,
                            const float* __restrict__ l2b, float* __restrict__ out,
                            int NCMT, int HFC, int NCLS, int BS) {
  int b = blockIdx.x;
  __shared__ float sbuf[400];
  __shared__ float z1[200];
  __shared__ float z2[8];
  int t = threadIdx.x;  // 256
  for (int c = t; c < NCMT; c += 256) {
    float cn = fmaxf(cntc[c], 1.0f);
    sbuf[c] = s_sum[c * BS + b] / cn + fcb[0];
  }
  __syncthreads();
  for (int j = t; j < HFC; j += 256) {
    float a = l1b[j];
    for (int c = 0; c < NCMT; ++c) a = fmaf(sbuf[c], l1w[j * NCMT + c], a);
    z1[j] = fmaxf(a, 0.f);
  }
  __syncthreads();
  if (t < NCLS) {
    float a = l2b[t];
    for (int j = 0; j < HFC; ++j) a = fmaf(z1[j], l2w[t * HFC + j], a);
    z2[t] = a;
  }
  __syncthreads();
  if (t == 0) {
    float mx = z2[0];
    for (int k = 1; k < NCLS; ++k) mx = fmaxf(mx, z2[k]);
    float se = 0.f;
    for (int k = 0; k < NCLS; ++k) se += expf(z2[k] - mx);
    float lse = mx + logf(se);
    for (int k = 0; k < NCLS; ++k) out[b * NCLS + k] = z2[k] - lse;
  }
}

extern "C" void kernel_launch(void* const* d_in, const int* in_sizes, int n_in,
                              void* d_out, int out_size, void* d_ws, size_t ws_size,
                              hipStream_t stream) {
  const float* x   = (const float*)d_in[0];
  const int*  ei   = (const int*)d_in[2];
  const int*  row  = (const int*)d_in[3];
  const int*  col  = (const int*)d_in[4];
  const float* W1  = (const float*)d_in[5];
  const float* b1  = (const float*)d_in[6];
  const float* W2  = (const float*)d_in[7];
  const float* b2  = (const float*)d_in[8];
  const float* W3  = (const float*)d_in[9];
  const float* b3  = (const float*)d_in[10];
  const float* fcw = (const float*)d_in[11];
  const float* fcb = (const float*)d_in[12];
  const float* l1w = (const float*)d_in[13];
  const float* l1b = (const float*)d_in[14];
  const float* l2w = (const float*)d_in[15];
  const float* l2b = (const float*)d_in[16];

  const int BS   = in_sizes[1];               // 8
  const int H    = in_sizes[6];               // 64
  const int F    = in_sizes[5] / H;           // 64
  const int N    = in_sizes[0] / (BS * F);    // 15135
  const int E    = in_sizes[2] / 2;           // 300000
  const int R    = in_sizes[3];               // 40000
  const int HFC  = in_sizes[14];              // 200
  const int NCMT = in_sizes[13] / HFC;        // 400
  const int NCLS = in_sizes[16];              // 2
  const int L    = in_sizes[11] / H;          // 3

  // workspace carve-out (256B aligned)
  char* p = (char*)d_ws;
  auto alloc = [&](size_t bytes) {
    void* r = (void*)p;
    p += (bytes + 255) & ~(size_t)255;
    return r;
  };
  int*   degi      = (int*)alloc((size_t)N * 4);
  int*   cursor    = (int*)alloc((size_t)N * 4);
  int*   row_start = (int*)alloc((size_t)(N + 1) * 4);
  int*   csr       = (int*)alloc((size_t)E * 4);
  float* dinv      = (float*)alloc((size_t)N * 4);
  float* q         = (float*)alloc((size_t)N * BS * 4);
  float* s_sum     = (float*)alloc((size_t)NCMT * BS * 4);
  float* cntc      = (float*)alloc((size_t)NCMT * 4);
  float* m         = (float*)alloc((size_t)N * BS * H * 4);
  float* hA        = (float*)alloc((size_t)N * BS * H * 4);
  float* hB        = (float*)alloc((size_t)N * BS * H * 4);

  hipMemsetAsync(degi, 0, (size_t)N * 4, stream);
  hipMemsetAsync(cursor, 0, (size_t)N * 4, stream);
  hipMemsetAsync(s_sum, 0, (size_t)NCMT * BS * 4, stream);
  hipMemsetAsync(cntc, 0, (size_t)NCMT * 4, stream);

  const int* e_src = ei;
  const int* e_dst = ei + E;

  count_kernel<<<(E + 255) / 256, 256, 0, stream>>>(e_dst, degi, E);
  prefix_kernel<<<1, 1024, 0, stream>>>(degi, row_start, N);
  fill_kernel<<<(E + 255) / 256, 256, 0, stream>>>(e_src, e_dst, row_start, cursor, csr, E);
  dinv_kernel<<<(N + 255) / 256, 256, 0, stream>>>(degi, dinv, N);

  int lin_grid = ((N + 63) / 64) * BS;   // b = blockIdx % BS -> XCD-pinned slices
  int agg_grid = ((N + 7) / 8) * BS;
  int agg_threads = 512;                 // 8 waves = 8 nodes per block

  // layer 1 (x is natively [b][n][f] — same indexing as internal layout)
  linear_kernel<<<lin_grid, 256, 0, stream>>>(x, W1, m, N, BS);
  agg_kernel<true><<<agg_grid, agg_threads, 0, stream>>>(m, dinv, b1, row_start, csr, hA, q, fcw, 0, L, N, BS);
  // layer 2
  linear_kernel<<<lin_grid, 256, 0, stream>>>(hA, W2, m, N, BS);
  agg_kernel<true><<<agg_grid, agg_threads, 0, stream>>>(m, dinv, b2, row_start, csr, hB, q, fcw, 1, L, N, BS);
  // layer 3 — hout is dead (only q survives), skip the store
  linear_kernel<<<lin_grid, 256, 0, stream>>>(hB, W3, m, N, BS);
  agg_kernel<false><<<agg_grid, agg_threads, 0, stream>>>(m, dinv, b3, row_start, csr, nullptr, q, fcw, 2, L, N, BS);

  pathway_kernel<<<((size_t)R * BS + 255) / 256, 256, 0, stream>>>(row, col, q, s_sum, cntc, R, N, BS);
  head_kernel<<<BS, 256, 0, stream>>>(s_sum, cntc, fcb, l1w, l1b, l2w, l2b,
                                      (float*)d_out, NCMT, HFC, NCLS, BS);
}

// Round 7
// 541.380 us; speedup vs baseline: 3.8076x; 1.1319x over previous
//
#include <hip/hip_runtime.h>

// ---------------------------------------------------------------------------
// GCNModelWPathways: 3-layer GCN (N nodes, BS=8 batch, H=64) + committee
// pathway pooling + 2-layer MLP head + log_softmax.
//
// Layout strategy (R5): all node features stored [b][n][h]. One b-slice =
// N*64*4B = 3.87 MB -> fits one XCD's 4 MB L2. linear and agg map
// b = blockIdx % 8 so each XCD owns one batch slice (perf heuristic only).
//
// R6: agg restructured: (1) dinv pre-scaling folded into linear's epilogue
// (ms = dinv ⊙ (h W^T)), so the edge body is a pure gather-add;
// (2) float4 lane remap — lane=(edge-slot, h-quad): one wave instruction
// gathers 4 edges x 256B, 4 independent L2 chains in flight.
//
// R4 lesson kept: __launch_bounds__(256,1) on linear — without it the
// backend targets the 64-VGPR tier and spills the 4x4 tile (~1.6 GB scratch).
// ---------------------------------------------------------------------------

__global__ void count_kernel(const int* __restrict__ dst, int* __restrict__ degi, int E) {
  int e = blockIdx.x * blockDim.x + threadIdx.x;
  if (e < E) atomicAdd(&degi[dst[e]], 1);
}

// single-block exclusive prefix sum over counts[0..n) -> row_start[0..n]
__global__ void prefix_kernel(const int* __restrict__ counts, int* __restrict__ row_start, int n) {
  __shared__ int sums[1024];
  int t = threadIdx.x;
  int chunk = (n + 1023) >> 10;
  int beg = t * chunk;
  int end = min(beg + chunk, n);
  int s = 0;
  for (int i = beg; i < end; ++i) s += counts[i];
  sums[t] = s;
  __syncthreads();
  for (int d = 1; d < 1024; d <<= 1) {
    int v = (t >= d) ? sums[t - d] : 0;
    __syncthreads();
    sums[t] += v;
    __syncthreads();
  }
  int off = (t == 0) ? 0 : sums[t - 1];
  for (int i = beg; i < end; ++i) { row_start[i] = off; off += counts[i]; }
  if (end == n) row_start[n] = off;  // all such threads write the total
}

__global__ void fill_kernel(const int* __restrict__ src, const int* __restrict__ dst,
                            const int* __restrict__ row_start, int* __restrict__ cursor,
                            int* __restrict__ csr, int E) {
  int e = blockIdx.x * blockDim.x + threadIdx.x;
  if (e < E) {
    int d = dst[e];
    int pos = atomicAdd(&cursor[d], 1);
    csr[row_start[d] + pos] = src[e];
  }
}

__global__ void dinv_kernel(const int* __restrict__ degi, float* __restrict__ dinv, int N) {
  int n = blockIdx.x * blockDim.x + threadIdx.x;
  if (n < N) dinv[n] = rsqrtf((float)(degi[n] + 1));  // +1: self-loop
}

// Register-tiled linear on one b-slice:
//   ms[b][r][h] = dinv[r] * sum_f H[b][r][f] * W[h][f]
// Grid = ceil(N/64) * BS blocks; b = blockIdx % BS (XCD-aligned), 256 threads,
// 64 rows x 64 h per block, 4x4 tile per thread in named float4 registers.
__global__ __launch_bounds__(256, 1)  // release VGPR budget; no 64-reg tier spills
void linear_kernel(const float* __restrict__ hin, const float* __restrict__ W,
                   const float* __restrict__ dinv, float* __restrict__ ms,
                   int N, int BS) {
  __shared__ __align__(16) float Xs[64][68];
  __shared__ __align__(16) float Wt[64][68];  // Wt[f][h]
  int t = threadIdx.x;
  int b = blockIdx.x % BS;
  int chunk = blockIdx.x / BS;
  int row0 = chunk * 64;                 // node index within slice
  int nrows = min(64, N - row0);
  size_t sbase = ((size_t)b * N + row0) * 64;

  // stage W transposed (coalesced read, scattered LDS write; once per block)
  for (int i = t; i < 4096; i += 256) {
    int h = i >> 6, f = i & 63;
    Wt[f][h] = W[i];
  }
  // stage X tile: 4 threads per row, each covers 4 float4s (stride 4)
  {
    int rr = t >> 2;   // 0..63
    int c0 = t & 3;
    bool valid = rr < nrows;
    const float* src = hin + sbase + (size_t)rr * 64;
#pragma unroll
    for (int c = 0; c < 4; ++c) {
      int f4 = c0 + c * 4;
      float4 v = valid ? reinterpret_cast<const float4*>(src)[f4]
                       : float4{0.f, 0.f, 0.f, 0.f};
      *reinterpret_cast<float4*>(&Xs[rr][4 * f4]) = v;
    }
  }
  __syncthreads();

  int hg = t & 15;   // h0 = 4*hg
  int rg = t >> 4;   // r0 = 4*rg
  int r0 = 4 * rg;

  float4 acc0 = {0.f, 0.f, 0.f, 0.f};
  float4 acc1 = {0.f, 0.f, 0.f, 0.f};
  float4 acc2 = {0.f, 0.f, 0.f, 0.f};
  float4 acc3 = {0.f, 0.f, 0.f, 0.f};

// NOTE: macro params must NOT be named x/y/z/w (round-3 compile failure).
#define FMA4(A, S, V)            \
  A.x = fmaf((S), (V).x, A.x);   \
  A.y = fmaf((S), (V).y, A.y);   \
  A.z = fmaf((S), (V).z, A.z);   \
  A.w = fmaf((S), (V).w, A.w);

#pragma unroll
  for (int i = 0; i < 16; ++i) {  // f0 = 4*i
    float4 xr0 = *reinterpret_cast<const float4*>(&Xs[r0 + 0][4 * i]);
    float4 xr1 = *reinterpret_cast<const float4*>(&Xs[r0 + 1][4 * i]);
    float4 xr2 = *reinterpret_cast<const float4*>(&Xs[r0 + 2][4 * i]);
    float4 xr3 = *reinterpret_cast<const float4*>(&Xs[r0 + 3][4 * i]);
    float4 wv0 = *reinterpret_cast<const float4*>(&Wt[4 * i + 0][4 * hg]);
    float4 wv1 = *reinterpret_cast<const float4*>(&Wt[4 * i + 1][4 * hg]);
    float4 wv2 = *reinterpret_cast<const float4*>(&Wt[4 * i + 2][4 * hg]);
    float4 wv3 = *reinterpret_cast<const float4*>(&Wt[4 * i + 3][4 * hg]);
    FMA4(acc0, xr0.x, wv0); FMA4(acc0, xr0.y, wv1); FMA4(acc0, xr0.z, wv2); FMA4(acc0, xr0.w, wv3);
    FMA4(acc1, xr1.x, wv0); FMA4(acc1, xr1.y, wv1); FMA4(acc1, xr1.z, wv2); FMA4(acc1, xr1.w, wv3);
    FMA4(acc2, xr2.x, wv0); FMA4(acc2, xr2.y, wv1); FMA4(acc2, xr2.z, wv2); FMA4(acc2, xr2.w, wv3);
    FMA4(acc3, xr3.x, wv0); FMA4(acc3, xr3.y, wv1); FMA4(acc3, xr3.z, wv2); FMA4(acc3, xr3.w, wv3);
  }
#undef FMA4

  // dinv pre-scaling epilogue: ms = dinv[row] * (h W^T)
  if (r0 + 0 < nrows) {
    float d = dinv[row0 + r0 + 0];
    acc0.x *= d; acc0.y *= d; acc0.z *= d; acc0.w *= d;
    reinterpret_cast<float4*>(&ms[sbase + (size_t)(r0 + 0) * 64])[hg] = acc0;
  }
  if (r0 + 1 < nrows) {
    float d = dinv[row0 + r0 + 1];
    acc1.x *= d; acc1.y *= d; acc1.z *= d; acc1.w *= d;
    reinterpret_cast<float4*>(&ms[sbase + (size_t)(r0 + 1) * 64])[hg] = acc1;
  }
  if (r0 + 2 < nrows) {
    float d = dinv[row0 + r0 + 2];
    acc2.x *= d; acc2.y *= d; acc2.z *= d; acc2.w *= d;
    reinterpret_cast<float4*>(&ms[sbase + (size_t)(r0 + 2) * 64])[hg] = acc2;
  }
  if (r0 + 3 < nrows) {
    float d = dinv[row0 + r0 + 3];
    acc3.x *= d; acc3.y *= d; acc3.z *= d; acc3.w *= d;
    reinterpret_cast<float4*>(&ms[sbase + (size_t)(r0 + 3) * 64])[hg] = acc3;
  }
}

// Pull aggregation on one b-slice. Grid = ceil(N/8) * BS; b = blockIdx % BS
// (XCD-aligned). Block = 512 threads = 8 waves; wave = one node.
// Lane remap: eg = lane>>4 (edge slot 0..3), hq = lane&15 (h quad).
// Inner loop: 4 edges per step, each lane does one float4 gather-add from the
// L2-resident dinv-prescaled ms slice. h = relu(dn * sum + bias).
template <bool WRITE_H>
__global__ void agg_kernel(const float* __restrict__ ms, const float* __restrict__ dinv,
                           const float* __restrict__ bias, const int* __restrict__ row_start,
                           const int* __restrict__ csr, float* __restrict__ hout,
                           float* __restrict__ q, const float* __restrict__ fcw,
                           int layer, int L, int N, int BS) {
  int b = blockIdx.x % BS;
  int chunk = blockIdx.x / BS;
  int w = threadIdx.x >> 6, lane = threadIdx.x & 63;
  int n = chunk * 8 + w;
  if (n >= N) return;
  int eg = lane >> 4;     // edge slot
  int hq = lane & 15;     // h quad: h = 4*hq .. 4*hq+3
  size_t bN = (size_t)b * N;
  const float* mb = ms + bN * 64;

  // self-loop (counted once — eg 0 only)
  float4 sv = *reinterpret_cast<const float4*>(&mb[(size_t)n * 64 + 4 * hq]);
  float4 acc = (eg == 0) ? sv : float4{0.f, 0.f, 0.f, 0.f};

  int beg = row_start[n], end = row_start[n + 1];
  int deg = end - beg;
  int i = beg;
  int main_end = beg + (deg & ~3);
  for (; i < main_end; i += 4) {
    int s = csr[i + eg];
    const float4 v = *reinterpret_cast<const float4*>(&mb[(size_t)s * 64 + 4 * hq]);
    acc.x += v.x; acc.y += v.y; acc.z += v.z; acc.w += v.w;
  }
  int rem = end - i;  // 0..3
  if (rem > 0) {
    int e = i + ((eg < rem) ? eg : 0);
    int s = csr[e];
    const float4 v = *reinterpret_cast<const float4*>(&mb[(size_t)s * 64 + 4 * hq]);
    if (eg < rem) { acc.x += v.x; acc.y += v.y; acc.z += v.z; acc.w += v.w; }
  }

  // reduce across the 4 edge-slot groups (lanes differing in bits 4,5)
  acc.x += __shfl_xor(acc.x, 16); acc.y += __shfl_xor(acc.y, 16);
  acc.z += __shfl_xor(acc.z, 16); acc.w += __shfl_xor(acc.w, 16);
  acc.x += __shfl_xor(acc.x, 32); acc.y += __shfl_xor(acc.y, 32);
  acc.z += __shfl_xor(acc.z, 32); acc.w += __shfl_xor(acc.w, 32);

  float dn = dinv[n];
  float4 bias4 = *reinterpret_cast<const float4*>(&bias[4 * hq]);
  float4 val;
  val.x = fmaxf(fmaf(dn, acc.x, bias4.x), 0.f);
  val.y = fmaxf(fmaf(dn, acc.y, bias4.y), 0.f);
  val.z = fmaxf(fmaf(dn, acc.z, bias4.z), 0.f);
  val.w = fmaxf(fmaf(dn, acc.w, bias4.w), 0.f);

  if (WRITE_H && eg == 0)
    *reinterpret_cast<float4*>(&hout[bN * 64 + (size_t)n * 64 + 4 * hq]) = val;

  // fc_w projection: q[n,b] (+)= sum_h val[h]*fcw[h*L+layer]
  int h0 = 4 * hq;
  float qp = val.x * fcw[(h0 + 0) * L + layer]
           + val.y * fcw[(h0 + 1) * L + layer]
           + val.z * fcw[(h0 + 2) * L + layer]
           + val.w * fcw[(h0 + 3) * L + layer];
  qp += __shfl_xor(qp, 1); qp += __shfl_xor(qp, 2);
  qp += __shfl_xor(qp, 4); qp += __shfl_xor(qp, 8);
  if (lane == 0) {
    if (layer == 0) q[bN + n] = qp;
    else q[bN + n] += qp;
  }
}

__global__ void pathway_kernel(const int* __restrict__ row, const int* __restrict__ col,
                               const float* __restrict__ q, float* __restrict__ s_sum,
                               float* __restrict__ cntc, int R, int N, int BS) {
  int idx = blockIdx.x * blockDim.x + threadIdx.x;
  if (idx >= R * BS) return;
  int r = idx / BS, b = idx - (idx / BS) * BS;
  int c = col[r], nd = row[r];
  atomicAdd(&s_sum[c * BS + b], q[(size_t)b * N + nd]);
  if (b == 0) atomicAdd(&cntc[c], 1.0f);
}

__global__ void head_kernel(const float* __restrict__ s_sum, const float* __restrict__ cntc,
                            const float* __restrict__ fcb, const float* __restrict__ l1w,
                            const float* __restrict__ l1b, const float* __restrict__ l2w,
                            const float* __restrict__ l2b, float* __restrict__ out,
                            int NCMT, int HFC, int NCLS, int BS) {
  int b = blockIdx.x;
  __shared__ float sbuf[400];
  __shared__ float z1[200];
  __shared__ float z2[8];
  int t = threadIdx.x;  // 256
  for (int c = t; c < NCMT; c += 256) {
    float cn = fmaxf(cntc[c], 1.0f);
    sbuf[c] = s_sum[c * BS + b] / cn + fcb[0];
  }
  __syncthreads();
  for (int j = t; j < HFC; j += 256) {
    float a = l1b[j];
    for (int c = 0; c < NCMT; ++c) a = fmaf(sbuf[c], l1w[j * NCMT + c], a);
    z1[j] = fmaxf(a, 0.f);
  }
  __syncthreads();
  if (t < NCLS) {
    float a = l2b[t];
    for (int j = 0; j < HFC; ++j) a = fmaf(z1[j], l2w[t * HFC + j], a);
    z2[t] = a;
  }
  __syncthreads();
  if (t == 0) {
    float mx = z2[0];
    for (int k = 1; k < NCLS; ++k) mx = fmaxf(mx, z2[k]);
    float se = 0.f;
    for (int k = 0; k < NCLS; ++k) se += expf(z2[k] - mx);
    float lse = mx + logf(se);
    for (int k = 0; k < NCLS; ++k) out[b * NCLS + k] = z2[k] - lse;
  }
}

extern "C" void kernel_launch(void* const* d_in, const int* in_sizes, int n_in,
                              void* d_out, int out_size, void* d_ws, size_t ws_size,
                              hipStream_t stream) {
  const float* x   = (const float*)d_in[0];
  const int*  ei   = (const int*)d_in[2];
  const int*  row  = (const int*)d_in[3];
  const int*  col  = (const int*)d_in[4];
  const float* W1  = (const float*)d_in[5];
  const float* b1  = (const float*)d_in[6];
  const float* W2  = (const float*)d_in[7];
  const float* b2  = (const float*)d_in[8];
  const float* W3  = (const float*)d_in[9];
  const float* b3  = (const float*)d_in[10];
  const float* fcw = (const float*)d_in[11];
  const float* fcb = (const float*)d_in[12];
  const float* l1w = (const float*)d_in[13];
  const float* l1b = (const float*)d_in[14];
  const float* l2w = (const float*)d_in[15];
  const float* l2b = (const float*)d_in[16];

  const int BS   = in_sizes[1];               // 8
  const int H    = in_sizes[6];               // 64
  const int F    = in_sizes[5] / H;           // 64
  const int N    = in_sizes[0] / (BS * F);    // 15135
  const int E    = in_sizes[2] / 2;           // 300000
  const int R    = in_sizes[3];               // 40000
  const int HFC  = in_sizes[14];              // 200
  const int NCMT = in_sizes[13] / HFC;        // 400
  const int NCLS = in_sizes[16];              // 2
  const int L    = in_sizes[11] / H;          // 3

  // workspace carve-out (256B aligned)
  char* p = (char*)d_ws;
  auto alloc = [&](size_t bytes) {
    void* r = (void*)p;
    p += (bytes + 255) & ~(size_t)255;
    return r;
  };
  int*   degi      = (int*)alloc((size_t)N * 4);
  int*   cursor    = (int*)alloc((size_t)N * 4);
  int*   row_start = (int*)alloc((size_t)(N + 1) * 4);
  int*   csr       = (int*)alloc((size_t)E * 4);
  float* dinv      = (float*)alloc((size_t)N * 4);
  float* q         = (float*)alloc((size_t)N * BS * 4);
  float* s_sum     = (float*)alloc((size_t)NCMT * BS * 4);
  float* cntc      = (float*)alloc((size_t)NCMT * 4);
  float* m         = (float*)alloc((size_t)N * BS * H * 4);
  float* hA        = (float*)alloc((size_t)N * BS * H * 4);
  float* hB        = (float*)alloc((size_t)N * BS * H * 4);

  hipMemsetAsync(degi, 0, (size_t)N * 4, stream);
  hipMemsetAsync(cursor, 0, (size_t)N * 4, stream);
  hipMemsetAsync(s_sum, 0, (size_t)NCMT * BS * 4, stream);
  hipMemsetAsync(cntc, 0, (size_t)NCMT * 4, stream);

  const int* e_src = ei;
  const int* e_dst = ei + E;

  count_kernel<<<(E + 255) / 256, 256, 0, stream>>>(e_dst, degi, E);
  prefix_kernel<<<1, 1024, 0, stream>>>(degi, row_start, N);
  fill_kernel<<<(E + 255) / 256, 256, 0, stream>>>(e_src, e_dst, row_start, cursor, csr, E);
  dinv_kernel<<<(N + 255) / 256, 256, 0, stream>>>(degi, dinv, N);

  int lin_grid = ((N + 63) / 64) * BS;   // b = blockIdx % BS -> XCD-pinned slices
  int agg_grid = ((N + 7) / 8) * BS;
  int agg_threads = 512;                 // 8 waves = 8 nodes per block

  // layer 1 (x is natively [b][n][f] — same indexing as internal layout)
  linear_kernel<<<lin_grid, 256, 0, stream>>>(x, W1, dinv, m, N, BS);
  agg_kernel<true><<<agg_grid, agg_threads, 0, stream>>>(m, dinv, b1, row_start, csr, hA, q, fcw, 0, L, N, BS);
  // layer 2
  linear_kernel<<<lin_grid, 256, 0, stream>>>(hA, W2, dinv, m, N, BS);
  agg_kernel<true><<<agg_grid, agg_threads, 0, stream>>>(m, dinv, b2, row_start, csr, hB, q, fcw, 1, L, N, BS);
  // layer 3 — hout is dead (only q survives), skip the store
  linear_kernel<<<lin_grid, 256, 0, stream>>>(hB, W3, dinv, m, N, BS);
  agg_kernel<false><<<agg_grid, agg_threads, 0, stream>>>(m, dinv, b3, row_start, csr, nullptr, q, fcw, 2, L, N, BS);

  pathway_kernel<<<((size_t)R * BS + 255) / 256, 256, 0, stream>>>(row, col, q, s_sum, cntc, R, N, BS);
  head_kernel<<<BS, 256, 0, stream>>>(s_sum, cntc, fcb, l1w, l1b, l2w, l2b,
                                      (float*)d_out, NCMT, HFC, NCLS, BS);
}